// Round 1
// baseline (138.201 us; speedup 1.0000x reference)
//
#include <hip/hip_runtime.h>

#define NB 16
#define NL 64
#define ND 256
#define NU 500
#define NV 10000
#define MINWL 4
#define MAXWL 10
#define NWL 7
#define ITEMP 10.0f  // 1/TEMP

// ---------------- kernel 0: normalize unit_repr rows ----------------
__global__ __launch_bounds__(256) void k_unorm(const float* __restrict__ unit,
                                               float* __restrict__ un) {
    int u = blockIdx.x, t = threadIdx.x;  // t == d (ND == 256)
    float v = unit[u * ND + t];
    float s = v * v;
#pragma unroll
    for (int o = 32; o >= 1; o >>= 1) s += __shfl_down(s, o);
    __shared__ float red[4];
    __shared__ float scale;
    if ((t & 63) == 0) red[t >> 6] = s;
    __syncthreads();
    if (t == 0) scale = 1.0f / sqrtf(red[0] + red[1] + red[2] + red[3]);
    __syncthreads();
    un[u * ND + t] = v * scale;
}

// ---------------- kernel 1: sim = wn @ un^T  (B*L x U, K=256) ----------------
#define LT 16
#define UC 64
#define SSTR 260  // padded row stride (floats); 260%32==4 -> balanced b128 banks
#define SIM_LDS_BYTES ((LT + UC) * SSTR * 4)

__global__ __launch_bounds__(256) void k_sim(const float* __restrict__ word,
                                             const float* __restrict__ un,
                                             float* __restrict__ sim) {
    extern __shared__ float lds[];
    float* wt = lds;             // [LT][SSTR]
    float* ut = lds + LT * SSTR; // [UC][SSTR]
    __shared__ float scale[LT];
    int blk = blockIdx.x;  // b*32 + lt*8 + uc
    int uc = blk & 7, lt = (blk >> 3) & 3, b = blk >> 5;
    int l0 = lt * LT, u0 = uc * UC;
    int t = threadIdx.x;

    // stage word tile (16 rows x 256)
#pragma unroll
    for (int i = 0; i < LT; ++i)
        wt[i * SSTR + t] = word[(b * NL + l0 + i) * ND + t];
    __syncthreads();
    // row norms: 16 threads/row, 16 cols each
    {
        int r = t >> 4, p = t & 15;
        float ss = 0.f;
#pragma unroll
        for (int c = 0; c < 16; ++c) {
            float x = wt[r * SSTR + p * 16 + c];
            ss += x * x;
        }
#pragma unroll
        for (int o = 1; o < 16; o <<= 1) ss += __shfl_xor(ss, o);
        if (p == 0) scale[r] = 1.0f / sqrtf(ss);
    }
    __syncthreads();
#pragma unroll
    for (int i = 0; i < LT; ++i) wt[i * SSTR + t] *= scale[i];
    // stage unit tile (64 rows x 256), already normalized
#pragma unroll
    for (int i = 0; i < UC; ++i) {
        int u = u0 + i;
        ut[i * SSTR + t] = (u < NU) ? un[u * ND + t] : 0.0f;
    }
    __syncthreads();

    // 2l x 2u micro-tile per thread
    int lane = t & 31;
    int lp = t >> 5;  // 0..7
    int l = lp * 2;
    const float4* w0p = (const float4*)(wt + l * SSTR);
    const float4* w1p = (const float4*)(wt + (l + 1) * SSTR);
    const float4* x0p = (const float4*)(ut + lane * SSTR);
    const float4* x1p = (const float4*)(ut + (lane + 32) * SSTR);
    float a00 = 0.f, a01 = 0.f, a10 = 0.f, a11 = 0.f;
#pragma unroll 8
    for (int dq = 0; dq < ND / 4; ++dq) {
        float4 w0 = w0p[dq], w1 = w1p[dq], x0 = x0p[dq], x1 = x1p[dq];
        a00 += w0.x * x0.x + w0.y * x0.y + w0.z * x0.z + w0.w * x0.w;
        a01 += w0.x * x1.x + w0.y * x1.y + w0.z * x1.z + w0.w * x1.w;
        a10 += w1.x * x0.x + w1.y * x0.y + w1.z * x0.z + w1.w * x0.w;
        a11 += w1.x * x1.x + w1.y * x1.y + w1.z * x1.z + w1.w * x1.w;
    }
    int gu0 = u0 + lane, gu1 = u0 + lane + 32;
    int base = (b * NL + l0 + l) * NU;
    if (gu0 < NU) { sim[base + gu0] = a00; sim[base + NU + gu0] = a10; }
    if (gu1 < NU) { sim[base + gu1] = a01; sim[base + NU + gu1] = a11; }
}

// ---------------- kernel 2: per-(b,s) soft-min over vocab ----------------
__global__ __launch_bounds__(256) void k_extract(const float* __restrict__ sim,
                                                 const int* __restrict__ seg,
                                                 const int* __restrict__ vlen,
                                                 float* __restrict__ dense,
                                                 int* __restrict__ mv) {
    int blk = blockIdx.x;  // b*64 + s
    int s = blk & (NL - 1), b = blk >> 6;
    int t = threadIdx.x;
    int wlmax = min(MAXWL, NL - s);
    if (wlmax < MINWL) {  // no viable span: zero dense row
        if (t < NL) dense[blk * NL + t] = 0.0f;
        return;
    }
    int kmax = wlmax - MINWL;  // 0..6, wave-uniform

    __shared__ float sl[MAXWL * NU];  // sim rows s..s+wlmax-1
    for (int j = 0; j < wlmax; ++j)
        for (int c = t; c < NU; c += 256)
            sl[j * NU + c] = sim[(b * NL + s + j) * NU + c];
    __syncthreads();

    float m[NWL], S[NWL], W[NWL];
    int ix[NWL];
#pragma unroll
    for (int k = 0; k < NWL; ++k) { m[k] = 3.0e38f; S[k] = 0.f; W[k] = 0.f; ix[k] = 0; }

    for (int v = t; v < NV; v += 256) {
        int len = vlen[v];
        const int2* sp = (const int2*)(seg + v * MAXWL);
        int2 p0 = sp[0], p1 = sp[1], p2 = sp[2], p3 = sp[3], p4 = sp[4];
        int sg[MAXWL] = {p0.x, p0.y, p1.x, p1.y, p2.x, p2.y, p3.x, p3.y, p4.x, p4.y};
        int jmax = min(wlmax, len);
        float d[MAXWL];
#pragma unroll
        for (int j = 0; j < MAXWL; ++j)
            d[j] = (j < jmax) ? (1.0f - sl[j * NU + sg[j]]) : 0.0f;
        // prefix chain in the reference's float association order
        float q = d[0] + d[1] + d[2] + d[3];  // pref[min(4,len)] (len>=4)
        float ed[NWL];
#pragma unroll
        for (int k = 0; k < NWL; ++k) {
            ed[k] = q + (float)abs(MINWL + k - len);
            if (k < NWL - 1) q += d[MINWL + k];  // d[]==0 past jmax -> exact
        }
        // online soft-min per k (uniform branch on kmax)
#pragma unroll
        for (int k = 0; k < NWL; ++k) {
            if (k <= kmax) {
                float e = ed[k];
                if (e < m[k]) {  // strict: keeps first occurrence within thread
                    float f = __expf((e - m[k]) * ITEMP);
                    S[k] = S[k] * f + 1.0f;
                    W[k] = W[k] * f + e;
                    m[k] = e;
                    ix[k] = v;
                } else {
                    float w = __expf((m[k] - e) * ITEMP);
                    S[k] += w;
                    W[k] += e * w;
                }
            }
        }
    }

    // wave-level reduction (min, rescaled sums, first-occurrence argmin)
#pragma unroll
    for (int k = 0; k < NWL; ++k) {
#pragma unroll
        for (int o = 32; o >= 1; o >>= 1) {
            float m2 = __shfl_down(m[k], o);
            float S2 = __shfl_down(S[k], o);
            float W2 = __shfl_down(W[k], o);
            int i2 = __shfl_down(ix[k], o);
            float mn = fminf(m[k], m2);
            float fa = __expf((mn - m[k]) * ITEMP);
            float fb = __expf((mn - m2) * ITEMP);
            S[k] = S[k] * fa + S2 * fb;
            W[k] = W[k] * fa + W2 * fb;
            ix[k] = (m2 < m[k] || (m2 == m[k] && i2 < ix[k])) ? i2 : ix[k];
            m[k] = mn;
        }
    }
    __shared__ float rm[4][NWL], rS[4][NWL], rW[4][NWL];
    __shared__ int rI[4][NWL];
    __shared__ float scoreRow[NWL];
    int wv = t >> 6;
    if ((t & 63) == 0) {
#pragma unroll
        for (int k = 0; k < NWL; ++k) {
            rm[wv][k] = m[k]; rS[wv][k] = S[k]; rW[wv][k] = W[k]; rI[wv][k] = ix[k];
        }
    }
    __syncthreads();
    if (t < NWL) {  // thread t == k
        int k = t;
        float mm = rm[0][k], SS = rS[0][k], WW = rW[0][k];
        int II = rI[0][k];
#pragma unroll
        for (int w2 = 1; w2 < 4; ++w2) {
            float m2 = rm[w2][k], S2 = rS[w2][k], W2 = rW[w2][k];
            int i2 = rI[w2][k];
            float mn = fminf(mm, m2);
            float fa = __expf((mn - mm) * ITEMP);
            float fb = __expf((mn - m2) * ITEMP);
            SS = SS * fa + S2 * fb;
            WW = WW * fa + W2 * fb;
            II = (m2 < mm || (m2 == mm && i2 < II)) ? i2 : II;
            mm = mn;
        }
        if (k <= kmax) {
            float med = WW / SS;              // matched_ed
            float wl = (float)(MINWL + k);
            float z = 1.0f - 2.0f * (med / wl);
            float cel = (z > 0.f) ? z : (__expf(z) - 1.0f);  // celu
            scoreRow[k] = 0.5f * (cel + 1.0f) * wl;
            mv[(b * NL + s) * NWL + k] = II;
        }
    }
    __syncthreads();
    if (t < NL) {  // dense row: e = t -> k = e-s-3
        int k = t - s - (MINWL - 1);
        float val = (k >= 0 && k <= kmax) ? scoreRow[k] : 0.0f;
        dense[blk * NL + t] = val;
    }
}

// ---------------- kernel 3: per-b soft-max over spans + outputs ----------------
__global__ __launch_bounds__(256) void k_final(const float* __restrict__ dense,
                                               const int* __restrict__ mv,
                                               float* __restrict__ out) {
    int b = blockIdx.x, t = threadIdx.x;
    float m = -3.0e38f, S = 0.f, W = 0.f;
    int ix = 0;
    for (int i = t; i < NL * NL; i += 256) {
        float x = dense[b * NL * NL + i];
        if (x > m) {  // strict: first occurrence within thread (ascending i)
            float f = __expf((m - x) * ITEMP);
            S = S * f + 1.0f;
            W = W * f + x;
            m = x;
            ix = i;
        } else {
            float w = __expf((x - m) * ITEMP);
            S += w;
            W += x * w;
        }
    }
#pragma unroll
    for (int o = 32; o >= 1; o >>= 1) {
        float m2 = __shfl_down(m, o);
        float S2 = __shfl_down(S, o);
        float W2 = __shfl_down(W, o);
        int i2 = __shfl_down(ix, o);
        float mx = fmaxf(m, m2);
        float fa = __expf((m - mx) * ITEMP);
        float fb = __expf((m2 - mx) * ITEMP);
        S = S * fa + S2 * fb;
        W = W * fa + W2 * fb;
        ix = (m2 > m || (m2 == m && i2 < ix)) ? i2 : ix;
        m = mx;
    }
    __shared__ float rm[4], rS[4], rW[4];
    __shared__ int rI[4];
    if ((t & 63) == 0) { int wv = t >> 6; rm[wv] = m; rS[wv] = S; rW[wv] = W; rI[wv] = ix; }
    __syncthreads();
    if (t == 0) {
        float mm = rm[0], SS = rS[0], WW = rW[0];
        int II = rI[0];
#pragma unroll
        for (int wv = 1; wv < 4; ++wv) {
            float m2 = rm[wv], S2 = rS[wv], W2 = rW[wv];
            int i2 = rI[wv];
            float mx = fmaxf(mm, m2);
            float fa = __expf((mm - mx) * ITEMP);
            float fb = __expf((m2 - mx) * ITEMP);
            SS = SS * fa + S2 * fb;
            WW = WW * fa + W2 * fb;
            II = (m2 > mm || (m2 == mm && i2 < II)) ? i2 : II;
            mm = mx;
        }
        float best = WW / SS;
        int st = II >> 6, en = II & (NL - 1);
        int ks = en - st + 1 - MINWL;
        ks = ks < 0 ? 0 : (ks > NWL - 1 ? NWL - 1 : ks);
        int bv = mv[(b * NL + st) * NWL + ks];
        out[b] = (float)st;
        out[NB + b] = (float)en;
        out[2 * NB + b] = best;
        out[3 * NB + b] = (float)bv;
    }
}

extern "C" void kernel_launch(void* const* d_in, const int* in_sizes, int n_in,
                              void* d_out, int out_size, void* d_ws, size_t ws_size,
                              hipStream_t stream) {
    const float* word = (const float*)d_in[0];   // (B,L,D) f32
    const float* unit = (const float*)d_in[1];   // (U,D) f32
    const int* seg = (const int*)d_in[2];        // (V,MAXWL) i32
    const int* vlen = (const int*)d_in[3];       // (V,) i32
    float* out = (float*)d_out;                  // [start|end|score|vocab|dense]
    char* ws = (char*)d_ws;
    float* sim = (float*)ws;                     // B*L*U f32 = 2,048,000 B
    float* un = (float*)(ws + 2048000);          // U*D f32  =   512,000 B
    int* mv = (int*)(ws + 2560000);              // B*L*NWL i32 = 28,672 B
    float* dense = out + 4 * NB;

    hipFuncSetAttribute((const void*)k_sim,
                        hipFuncAttributeMaxDynamicSharedMemorySize, SIM_LDS_BYTES);

    k_unorm<<<NU, 256, 0, stream>>>(unit, un);
    k_sim<<<NB * 4 * 8, 256, SIM_LDS_BYTES, stream>>>(word, un, sim);
    k_extract<<<NB * NL, 256, 0, stream>>>(sim, seg, vlen, dense, mv);
    k_final<<<NB, 256, 0, stream>>>(dense, mv, out);
}

// Round 2
// 81.305 us; speedup vs baseline: 1.6998x; 1.6998x over previous
//
#include <hip/hip_runtime.h>

#define NB 16
#define NL 64
#define ND 256
#define NU 500
#define NV 10000
#define MINWL 4
#define MAXWL 10
#define NWL 7
#define ITEMP 10.0f  // 1/TEMP

// ---------------- kernel 0: normalize unit_repr rows ----------------
__global__ __launch_bounds__(256) void k_unorm(const float* __restrict__ unit,
                                               float* __restrict__ un) {
    int u = blockIdx.x, t = threadIdx.x;  // t == d (ND == 256)
    float v = unit[u * ND + t];
    float s = v * v;
#pragma unroll
    for (int o = 32; o >= 1; o >>= 1) s += __shfl_down(s, o);
    __shared__ float red[4];
    __shared__ float scale;
    if ((t & 63) == 0) red[t >> 6] = s;
    __syncthreads();
    if (t == 0) scale = 1.0f / sqrtf(red[0] + red[1] + red[2] + red[3]);
    __syncthreads();
    un[u * ND + t] = v * scale;
}

// ---------------- kernel 1: sim = wn @ un^T  (B*L x U, K=256) ----------------
#define LT 16
#define UC 64
#define SSTR 260  // padded row stride (floats)
#define SIM_LDS_BYTES ((LT + UC) * SSTR * 4)

__global__ __launch_bounds__(256) void k_sim(const float* __restrict__ word,
                                             const float* __restrict__ un,
                                             float* __restrict__ sim) {
    extern __shared__ float lds[];
    float* wt = lds;             // [LT][SSTR]
    float* ut = lds + LT * SSTR; // [UC][SSTR]
    __shared__ float scale[LT];
    int blk = blockIdx.x;  // b*32 + lt*8 + uc
    int uc = blk & 7, lt = (blk >> 3) & 3, b = blk >> 5;
    int l0 = lt * LT, u0 = uc * UC;
    int t = threadIdx.x;

#pragma unroll
    for (int i = 0; i < LT; ++i)
        wt[i * SSTR + t] = word[(b * NL + l0 + i) * ND + t];
    __syncthreads();
    {
        int r = t >> 4, p = t & 15;
        float ss = 0.f;
#pragma unroll
        for (int c = 0; c < 16; ++c) {
            float x = wt[r * SSTR + p * 16 + c];
            ss += x * x;
        }
#pragma unroll
        for (int o = 1; o < 16; o <<= 1) ss += __shfl_xor(ss, o);
        if (p == 0) scale[r] = 1.0f / sqrtf(ss);
    }
    __syncthreads();
#pragma unroll
    for (int i = 0; i < LT; ++i) wt[i * SSTR + t] *= scale[i];
#pragma unroll
    for (int i = 0; i < UC; ++i) {
        int u = u0 + i;
        ut[i * SSTR + t] = (u < NU) ? un[u * ND + t] : 0.0f;
    }
    __syncthreads();

    int lane = t & 31;
    int lp = t >> 5;
    int l = lp * 2;
    const float4* w0p = (const float4*)(wt + l * SSTR);
    const float4* w1p = (const float4*)(wt + (l + 1) * SSTR);
    const float4* x0p = (const float4*)(ut + lane * SSTR);
    const float4* x1p = (const float4*)(ut + (lane + 32) * SSTR);
    float a00 = 0.f, a01 = 0.f, a10 = 0.f, a11 = 0.f;
#pragma unroll 8
    for (int dq = 0; dq < ND / 4; ++dq) {
        float4 w0 = w0p[dq], w1 = w1p[dq], x0 = x0p[dq], x1 = x1p[dq];
        a00 += w0.x * x0.x + w0.y * x0.y + w0.z * x0.z + w0.w * x0.w;
        a01 += w0.x * x1.x + w0.y * x1.y + w0.z * x1.z + w0.w * x1.w;
        a10 += w1.x * x0.x + w1.y * x0.y + w1.z * x0.z + w1.w * x0.w;
        a11 += w1.x * x1.x + w1.y * x1.y + w1.z * x1.z + w1.w * x1.w;
    }
    int gu0 = u0 + lane, gu1 = u0 + lane + 32;
    int base = (b * NL + l0 + l) * NU;
    if (gu0 < NU) { sim[base + gu0] = a00; sim[base + NU + gu0] = a10; }
    if (gu1 < NU) { sim[base + gu1] = a01; sim[base + NU + gu1] = a11; }
}

// ---------------- kernel 2: per-(b,s) soft-min over vocab ----------------
// Branch-free anchored soft-min: per-thread anchor m̂_k from the first vocab
// element; all weights w = exp((m̂-e)*10) are <= e^35 (no overflow; entries
// >6 below anchor underflow to their true ~0 contribution). Exact min/argmin
// tracked separately; sums rescaled to the thread-min reference before the
// (unchanged) wave/block merge.
__global__ __launch_bounds__(256, 4) void k_extract(const float* __restrict__ sim,
                                                    const int* __restrict__ seg,
                                                    const int* __restrict__ vlen,
                                                    float* __restrict__ dense,
                                                    int* __restrict__ mv) {
    int blk = blockIdx.x;  // b*64 + s
    int s = blk & (NL - 1), b = blk >> 6;
    int t = threadIdx.x;
    int wlmax = min(MAXWL, NL - s);
    if (wlmax < MINWL) {  // no viable span: zero dense row
        if (t < NL) dense[blk * NL + t] = 0.0f;
        return;
    }
    int kmax = wlmax - MINWL;  // 0..6, block-uniform

    __shared__ float sl[MAXWL * NU];  // sim rows s..s+wlmax-1
    for (int j = 0; j < wlmax; ++j)
        for (int c = t; c < NU; c += 256)
            sl[j * NU + c] = sim[(b * NL + s + j) * NU + c];
    __syncthreads();

    // ed in the reference's float association order (bit-exact prefix chain)
    auto comp_ed = [&](int2 a0, int2 a1, int2 a2, int2 a3, int2 a4, int L_,
                       float* ed) {
        int jmax = min(wlmax, L_);
        int sg[MAXWL] = {a0.x, a0.y, a1.x, a1.y, a2.x, a2.y, a3.x, a3.y, a4.x, a4.y};
        float d[MAXWL];
#pragma unroll
        for (int j = 0; j < 4; ++j)  // j<4 always < jmax (len>=4, wlmax>=4)
            d[j] = 1.0f - sl[j * NU + sg[j]];
#pragma unroll
        for (int j = 4; j < MAXWL; ++j) {
            float x = 1.0f - sl[j * NU + sg[j]];
            d[j] = (j < jmax) ? x : 0.0f;
        }
        float q = ((d[0] + d[1]) + d[2]) + d[3];
        float fl = (float)L_;
#pragma unroll
        for (int k = 0; k < NWL; ++k) {
            ed[k] = q + fabsf((float)(MINWL + k) - fl);  // exact small ints
            if (k < NWL - 1) q += d[MINWL + k];
        }
    };

    // current segment registers (v = t)
    int2 g0, g1, g2, g3, g4;
    int len;
    {
        const int2* sp = (const int2*)(seg + t * MAXWL);
        g0 = sp[0]; g1 = sp[1]; g2 = sp[2]; g3 = sp[3]; g4 = sp[4];
        len = vlen[t];
    }

    float m[NWL], S[NWL], W[NWL], m10[NWL];
    int ix[NWL];
    {
        float ed0[NWL];
        comp_ed(g0, g1, g2, g3, g4, len, ed0);
#pragma unroll
        for (int k = 0; k < NWL; ++k) {
            m[k] = 3.0e38f; S[k] = 0.0f; W[k] = 0.0f; ix[k] = 0;
            m10[k] = (ed0[k] - 4.0f) * 10.0f;  // anchor * ITEMP
        }
    }

    for (int v = t; v < NV; v += 256) {
        // prefetch next iteration's segment (clamped: no tail divergence)
        int vv = min(v + 256, NV - 1);
        int2 n0, n1, n2, n3, n4;
        int nlen;
        {
            const int2* sp = (const int2*)(seg + vv * MAXWL);
            n0 = sp[0]; n1 = sp[1]; n2 = sp[2]; n3 = sp[3]; n4 = sp[4];
            nlen = vlen[vv];
        }
        float ed[NWL];
        comp_ed(g0, g1, g2, g3, g4, len, ed);
#pragma unroll
        for (int k = 0; k < NWL; ++k) {
            float e = ed[k];
            bool lt = e < m[k];           // strict: first occurrence wins
            ix[k] = lt ? v : ix[k];
            m[k] = lt ? e : m[k];
            float w = __expf(fmaf(e, -ITEMP, m10[k]));  // exp((m̂-e)*10)
            S[k] += w;
            W[k] = fmaf(e, w, W[k]);
        }
        g0 = n0; g1 = n1; g2 = n2; g3 = n3; g4 = n4; len = nlen;
    }

    // rescale anchor-referenced sums to thread-min reference
#pragma unroll
    for (int k = 0; k < NWL; ++k) {
        float f = __expf(fmaf(m[k], ITEMP, -m10[k]));  // exp((m-m̂)*10)
        S[k] *= f;
        W[k] *= f;
    }

    // wave-level reduction (min, rescaled sums, first-occurrence argmin)
#pragma unroll
    for (int k = 0; k < NWL; ++k) {
#pragma unroll
        for (int o = 32; o >= 1; o >>= 1) {
            float m2 = __shfl_down(m[k], o);
            float S2 = __shfl_down(S[k], o);
            float W2 = __shfl_down(W[k], o);
            int i2 = __shfl_down(ix[k], o);
            float mn = fminf(m[k], m2);
            float fa = __expf((mn - m[k]) * ITEMP);
            float fb = __expf((mn - m2) * ITEMP);
            S[k] = S[k] * fa + S2 * fb;
            W[k] = W[k] * fa + W2 * fb;
            ix[k] = (m2 < m[k] || (m2 == m[k] && i2 < ix[k])) ? i2 : ix[k];
            m[k] = mn;
        }
    }
    __shared__ float rm[4][NWL], rS[4][NWL], rW[4][NWL];
    __shared__ int rI[4][NWL];
    __shared__ float scoreRow[NWL];
    int wv = t >> 6;
    if ((t & 63) == 0) {
#pragma unroll
        for (int k = 0; k < NWL; ++k) {
            rm[wv][k] = m[k]; rS[wv][k] = S[k]; rW[wv][k] = W[k]; rI[wv][k] = ix[k];
        }
    }
    __syncthreads();
    if (t < NWL) {  // thread t == k
        int k = t;
        float mm = rm[0][k], SS = rS[0][k], WW = rW[0][k];
        int II = rI[0][k];
#pragma unroll
        for (int w2 = 1; w2 < 4; ++w2) {
            float m2 = rm[w2][k], S2 = rS[w2][k], W2 = rW[w2][k];
            int i2 = rI[w2][k];
            float mn = fminf(mm, m2);
            float fa = __expf((mn - mm) * ITEMP);
            float fb = __expf((mn - m2) * ITEMP);
            SS = SS * fa + S2 * fb;
            WW = WW * fa + W2 * fb;
            II = (m2 < mm || (m2 == mm && i2 < II)) ? i2 : II;
            mm = mn;
        }
        if (k <= kmax) {
            float med = WW / SS;              // matched_ed
            float wl = (float)(MINWL + k);
            float z = 1.0f - 2.0f * (med / wl);
            float cel = (z > 0.f) ? z : (__expf(z) - 1.0f);  // celu
            scoreRow[k] = 0.5f * (cel + 1.0f) * wl;
            mv[(b * NL + s) * NWL + k] = II;
        }
    }
    __syncthreads();
    if (t < NL) {  // dense row: e = t -> k = e-s-3
        int k = t - s - (MINWL - 1);
        float val = (k >= 0 && k <= kmax) ? scoreRow[k] : 0.0f;
        dense[blk * NL + t] = val;
    }
}

// ---------------- kernel 3: per-b soft-max over spans + outputs ----------------
__global__ __launch_bounds__(256) void k_final(const float* __restrict__ dense,
                                               const int* __restrict__ mv,
                                               float* __restrict__ out) {
    int b = blockIdx.x, t = threadIdx.x;
    float m = -3.0e38f, S = 0.f, W = 0.f;
    int ix = 0;
    for (int i = t; i < NL * NL; i += 256) {
        float x = dense[b * NL * NL + i];
        if (x > m) {
            float f = __expf((m - x) * ITEMP);
            S = S * f + 1.0f;
            W = W * f + x;
            m = x;
            ix = i;
        } else {
            float w = __expf((x - m) * ITEMP);
            S += w;
            W += x * w;
        }
    }
#pragma unroll
    for (int o = 32; o >= 1; o >>= 1) {
        float m2 = __shfl_down(m, o);
        float S2 = __shfl_down(S, o);
        float W2 = __shfl_down(W, o);
        int i2 = __shfl_down(ix, o);
        float mx = fmaxf(m, m2);
        float fa = __expf((m - mx) * ITEMP);
        float fb = __expf((m2 - mx) * ITEMP);
        S = S * fa + S2 * fb;
        W = W * fa + W2 * fb;
        ix = (m2 > m || (m2 == m && i2 < ix)) ? i2 : ix;
        m = mx;
    }
    __shared__ float rm[4], rS[4], rW[4];
    __shared__ int rI[4];
    if ((t & 63) == 0) { int wv = t >> 6; rm[wv] = m; rS[wv] = S; rW[wv] = W; rI[wv] = ix; }
    __syncthreads();
    if (t == 0) {
        float mm = rm[0], SS = rS[0], WW = rW[0];
        int II = rI[0];
#pragma unroll
        for (int wv = 1; wv < 4; ++wv) {
            float m2 = rm[wv], S2 = rS[wv], W2 = rW[wv];
            int i2 = rI[wv];
            float mx = fmaxf(mm, m2);
            float fa = __expf((mm - mx) * ITEMP);
            float fb = __expf((m2 - mx) * ITEMP);
            SS = SS * fa + S2 * fb;
            WW = WW * fa + W2 * fb;
            II = (m2 > mm || (m2 == mm && i2 < II)) ? i2 : II;
            mm = mx;
        }
        float best = WW / SS;
        int st = II >> 6, en = II & (NL - 1);
        int ks = en - st + 1 - MINWL;
        ks = ks < 0 ? 0 : (ks > NWL - 1 ? NWL - 1 : ks);
        int bv = mv[(b * NL + st) * NWL + ks];
        out[b] = (float)st;
        out[NB + b] = (float)en;
        out[2 * NB + b] = best;
        out[3 * NB + b] = (float)bv;
    }
}

extern "C" void kernel_launch(void* const* d_in, const int* in_sizes, int n_in,
                              void* d_out, int out_size, void* d_ws, size_t ws_size,
                              hipStream_t stream) {
    const float* word = (const float*)d_in[0];   // (B,L,D) f32
    const float* unit = (const float*)d_in[1];   // (U,D) f32
    const int* seg = (const int*)d_in[2];        // (V,MAXWL) i32
    const int* vlen = (const int*)d_in[3];       // (V,) i32
    float* out = (float*)d_out;                  // [start|end|score|vocab|dense]
    char* ws = (char*)d_ws;
    float* sim = (float*)ws;                     // B*L*U f32 = 2,048,000 B
    float* un = (float*)(ws + 2048000);          // U*D f32  =   512,000 B
    int* mv = (int*)(ws + 2560000);              // B*L*NWL i32 = 28,672 B
    float* dense = out + 4 * NB;

    hipFuncSetAttribute((const void*)k_sim,
                        hipFuncAttributeMaxDynamicSharedMemorySize, SIM_LDS_BYTES);

    k_unorm<<<NU, 256, 0, stream>>>(unit, un);
    k_sim<<<NB * 4 * 8, 256, SIM_LDS_BYTES, stream>>>(word, un, sim);
    k_extract<<<NB * NL, 256, 0, stream>>>(sim, seg, vlen, dense, mv);
    k_final<<<NB, 256, 0, stream>>>(dense, mv, out);
}

// Round 3
// 70.865 us; speedup vs baseline: 1.9502x; 1.1473x over previous
//
#include <hip/hip_runtime.h>

#define NB 16
#define NL 64
#define ND 256
#define NU 500
#define NV 10000
#define MINWL 4
#define MAXWL 10
#define NWL 7
#define ITEMP 10.0f           // 1/TEMP
#define L2I 14.4269504088896f // 10 * log2(e)

// ---------------- kernel 1: sim = normalize(word) @ normalize(unit)^T ----------------
// Normalization folded into the epilogue: sim = (w·u) * (1/|w|) * (1/|u|).
#define LT 16
#define UC 32
#define SSTR 260  // padded row stride (floats); 260*4B is 16B-aligned

__global__ __launch_bounds__(256) void k_sim(const float* __restrict__ word,
                                             const float* __restrict__ unit,
                                             float* __restrict__ sim) {
    __shared__ float wt[LT * SSTR];   // raw word rows
    __shared__ float ut[UC * SSTR];   // raw unit rows
    __shared__ float scaleW[LT], scaleU[UC];
    int blk = blockIdx.x;  // b*64 + lt*16 + uc
    int uc = blk & 15, lt = (blk >> 4) & 3, b = blk >> 6;
    int l0 = lt * LT, u0 = uc * UC;
    int t = threadIdx.x;

#pragma unroll
    for (int i = 0; i < LT; ++i)
        wt[i * SSTR + t] = word[(b * NL + l0 + i) * ND + t];
#pragma unroll
    for (int i = 0; i < UC; ++i) {
        int u = u0 + i;
        ut[i * SSTR + t] = (u < NU) ? unit[u * ND + t] : 0.0f;
    }
    __syncthreads();
    {   // word row norms: 16 threads/row
        int r = t >> 4, p = t & 15;
        float ss = 0.f;
#pragma unroll
        for (int c = 0; c < 16; ++c) {
            float x = wt[r * SSTR + p * 16 + c];
            ss += x * x;
        }
#pragma unroll
        for (int o = 1; o < 16; o <<= 1) ss += __shfl_xor(ss, o);
        if (p == 0) scaleW[r] = 1.0f / sqrtf(ss);
    }
    {   // unit row norms: 8 threads/row
        int r = t >> 3, p = t & 7;
        float ss = 0.f;
#pragma unroll
        for (int c = 0; c < 32; ++c) {
            float x = ut[r * SSTR + p * 32 + c];
            ss += x * x;
        }
#pragma unroll
        for (int o = 1; o < 8; o <<= 1) ss += __shfl_xor(ss, o);
        if (p == 0) scaleU[r] = 1.0f / sqrtf(ss);
    }
    __syncthreads();

    int lane = t & 31;       // unit within tile
    int lp = t >> 5;         // 0..7
    int l = lp * 2;
    const float4* w0p = (const float4*)(wt + l * SSTR);
    const float4* w1p = (const float4*)(wt + (l + 1) * SSTR);
    const float4* x0p = (const float4*)(ut + lane * SSTR);
    float a00 = 0.f, a10 = 0.f;
#pragma unroll 8
    for (int dq = 0; dq < ND / 4; ++dq) {
        float4 w0 = w0p[dq], w1 = w1p[dq], x0 = x0p[dq];
        a00 += w0.x * x0.x + w0.y * x0.y + w0.z * x0.z + w0.w * x0.w;
        a10 += w1.x * x0.x + w1.y * x0.y + w1.z * x0.z + w1.w * x0.w;
    }
    int u = u0 + lane;
    if (u < NU) {
        float su = scaleU[lane];
        int base = (b * NL + l0 + l) * NU;
        sim[base + u] = a00 * (scaleW[l] * su);
        sim[base + NU + u] = a10 * (scaleW[l + 1] * su);
    }
}

// ---------------- kernel 2: per-(b,s) soft-min over vocab ----------------
// 512 threads (8 waves) for latency hiding. LDS holds d = 1-sim directly
// (bit-identical to computing 1-sim inline). Branch-free anchored soft-min
// with exp2; exact min/argmin tracked separately (first-occurrence exact).
#define NT 512

__global__ __launch_bounds__(NT, 8) void k_extract(const float* __restrict__ sim,
                                                   const int* __restrict__ seg,
                                                   const int* __restrict__ vlen,
                                                   float* __restrict__ dense,
                                                   int* __restrict__ mv) {
    int blk = blockIdx.x;  // b*64 + s
    int s = blk & (NL - 1), b = blk >> 6;
    int t = threadIdx.x;
    int wlmax = min(MAXWL, NL - s);
    if (wlmax < MINWL) {  // no viable span: zero dense row
        if (t < NL) dense[blk * NL + t] = 0.0f;
        return;
    }
    int kmax = wlmax - MINWL;  // 0..6, block-uniform

    __shared__ float dl[MAXWL * NU];  // d = 1 - sim rows s..s+wlmax-1
    for (int j = 0; j < wlmax; ++j)
        if (t < NU) dl[j * NU + t] = 1.0f - sim[(b * NL + s + j) * NU + t];
    __syncthreads();

    // ed in the reference's float association order (bit-exact prefix chain)
    auto comp_ed = [&](int2 a0, int2 a1, int2 a2, int2 a3, int2 a4, int L_,
                       float* ed) {
        int jmax = min(wlmax, L_);
        int sg[MAXWL] = {a0.x, a0.y, a1.x, a1.y, a2.x, a2.y, a3.x, a3.y, a4.x, a4.y};
        float d[MAXWL];
#pragma unroll
        for (int j = 0; j < 4; ++j)  // j<4 always < jmax (len>=4, wlmax>=4)
            d[j] = dl[j * NU + sg[j]];
#pragma unroll
        for (int j = 4; j < MAXWL; ++j) {
            float x = dl[j * NU + sg[j]];
            d[j] = (j < jmax) ? x : 0.0f;
        }
        float q = ((d[0] + d[1]) + d[2]) + d[3];
        float fl = (float)L_;
#pragma unroll
        for (int k = 0; k < NWL; ++k) {
            ed[k] = q + fabsf((float)(MINWL + k) - fl);  // exact small ints
            if (k < NWL - 1) q += d[MINWL + k];
        }
    };

    // current segment registers (v = t)
    int2 g0, g1, g2, g3, g4;
    int len;
    {
        const int2* sp = (const int2*)(seg + t * MAXWL);
        g0 = sp[0]; g1 = sp[1]; g2 = sp[2]; g3 = sp[3]; g4 = sp[4];
        len = vlen[t];
    }

    float m[NWL], S[NWL], W[NWL], mA[NWL];  // mA = anchor*10*log2e
    int ix[NWL];
    {
        float ed0[NWL];
        comp_ed(g0, g1, g2, g3, g4, len, ed0);
#pragma unroll
        for (int k = 0; k < NWL; ++k) {
            m[k] = 3.0e38f; S[k] = 0.0f; W[k] = 0.0f; ix[k] = 0;
            mA[k] = (ed0[k] - 4.0f) * L2I;
        }
    }

    for (int v = t; v < NV; v += NT) {
        // prefetch next iteration's segment (clamped: no tail divergence)
        int vv = min(v + NT, NV - 1);
        int2 n0, n1, n2, n3, n4;
        int nlen;
        {
            const int2* sp = (const int2*)(seg + vv * MAXWL);
            n0 = sp[0]; n1 = sp[1]; n2 = sp[2]; n3 = sp[3]; n4 = sp[4];
            nlen = vlen[vv];
        }
        float ed[NWL];
        comp_ed(g0, g1, g2, g3, g4, len, ed);
#pragma unroll
        for (int k = 0; k < NWL; ++k) {
            float e = ed[k];
            bool lt = e < m[k];           // strict: first occurrence wins
            ix[k] = lt ? v : ix[k];
            m[k] = lt ? e : m[k];
            float w = __builtin_amdgcn_exp2f(fmaf(e, -L2I, mA[k]));
            S[k] += w;
            W[k] = fmaf(e, w, W[k]);
        }
        g0 = n0; g1 = n1; g2 = n2; g3 = n3; g4 = n4; len = nlen;
    }

    // rescale anchor-referenced sums to thread-min reference
#pragma unroll
    for (int k = 0; k < NWL; ++k) {
        float f = __builtin_amdgcn_exp2f(fmaf(m[k], L2I, -mA[k]));
        S[k] *= f;
        W[k] *= f;
    }

    // wave-level reduction (min, rescaled sums, first-occurrence argmin)
#pragma unroll
    for (int k = 0; k < NWL; ++k) {
#pragma unroll
        for (int o = 32; o >= 1; o >>= 1) {
            float m2 = __shfl_down(m[k], o);
            float S2 = __shfl_down(S[k], o);
            float W2 = __shfl_down(W[k], o);
            int i2 = __shfl_down(ix[k], o);
            float mn = fminf(m[k], m2);
            float fa = __expf((mn - m[k]) * ITEMP);
            float fb = __expf((mn - m2) * ITEMP);
            S[k] = S[k] * fa + S2 * fb;
            W[k] = W[k] * fa + W2 * fb;
            ix[k] = (m2 < m[k] || (m2 == m[k] && i2 < ix[k])) ? i2 : ix[k];
            m[k] = mn;
        }
    }
    __shared__ float rm[8][NWL], rS[8][NWL], rW[8][NWL];
    __shared__ int rI[8][NWL];
    __shared__ float scoreRow[NWL];
    int wv = t >> 6;
    if ((t & 63) == 0) {
#pragma unroll
        for (int k = 0; k < NWL; ++k) {
            rm[wv][k] = m[k]; rS[wv][k] = S[k]; rW[wv][k] = W[k]; rI[wv][k] = ix[k];
        }
    }
    __syncthreads();
    if (t < NWL) {  // thread t == k
        int k = t;
        float mm = rm[0][k], SS = rS[0][k], WW = rW[0][k];
        int II = rI[0][k];
#pragma unroll
        for (int w2 = 1; w2 < 8; ++w2) {
            float m2 = rm[w2][k], S2 = rS[w2][k], W2 = rW[w2][k];
            int i2 = rI[w2][k];
            float mn = fminf(mm, m2);
            float fa = __expf((mn - mm) * ITEMP);
            float fb = __expf((mn - m2) * ITEMP);
            SS = SS * fa + S2 * fb;
            WW = WW * fa + W2 * fb;
            II = (m2 < mm || (m2 == mm && i2 < II)) ? i2 : II;
            mm = mn;
        }
        if (k <= kmax) {
            float med = WW / SS;              // matched_ed
            float wl = (float)(MINWL + k);
            float z = 1.0f - 2.0f * (med / wl);
            float cel = (z > 0.f) ? z : (__expf(z) - 1.0f);  // celu
            scoreRow[k] = 0.5f * (cel + 1.0f) * wl;
            mv[(b * NL + s) * NWL + k] = II;
        }
    }
    __syncthreads();
    if (t < NL) {  // dense row: e = t -> k = e-s-3
        int k = t - s - (MINWL - 1);
        float val = (k >= 0 && k <= kmax) ? scoreRow[k] : 0.0f;
        dense[blk * NL + t] = val;
    }
}

// ---------------- kernel 3: per-b soft-max over spans + outputs ----------------
__global__ __launch_bounds__(256) void k_final(const float* __restrict__ dense,
                                               const int* __restrict__ mv,
                                               float* __restrict__ out) {
    int b = blockIdx.x, t = threadIdx.x;
    float m = -3.0e38f, S = 0.f, W = 0.f;
    int ix = 0;
    for (int i = t; i < NL * NL; i += 256) {
        float x = dense[b * NL * NL + i];
        if (x > m) {
            float f = __expf((m - x) * ITEMP);
            S = S * f + 1.0f;
            W = W * f + x;
            m = x;
            ix = i;
        } else {
            float w = __expf((x - m) * ITEMP);
            S += w;
            W += x * w;
        }
    }
#pragma unroll
    for (int o = 32; o >= 1; o >>= 1) {
        float m2 = __shfl_down(m, o);
        float S2 = __shfl_down(S, o);
        float W2 = __shfl_down(W, o);
        int i2 = __shfl_down(ix, o);
        float mx = fmaxf(m, m2);
        float fa = __expf((m - mx) * ITEMP);
        float fb = __expf((m2 - mx) * ITEMP);
        S = S * fa + S2 * fb;
        W = W * fa + W2 * fb;
        ix = (m2 > m || (m2 == m && i2 < ix)) ? i2 : ix;
        m = mx;
    }
    __shared__ float rm[4], rS[4], rW[4];
    __shared__ int rI[4];
    if ((t & 63) == 0) { int wv = t >> 6; rm[wv] = m; rS[wv] = S; rW[wv] = W; rI[wv] = ix; }
    __syncthreads();
    if (t == 0) {
        float mm = rm[0], SS = rS[0], WW = rW[0];
        int II = rI[0];
#pragma unroll
        for (int wv = 1; wv < 4; ++wv) {
            float m2 = rm[wv], S2 = rS[wv], W2 = rW[wv];
            int i2 = rI[wv];
            float mx = fmaxf(mm, m2);
            float fa = __expf((mm - mx) * ITEMP);
            float fb = __expf((m2 - mx) * ITEMP);
            SS = SS * fa + S2 * fb;
            WW = WW * fa + W2 * fb;
            II = (m2 > mm || (m2 == mm && i2 < II)) ? i2 : II;
            mm = mx;
        }
        float best = WW / SS;
        int st = II >> 6, en = II & (NL - 1);
        int ks = en - st + 1 - MINWL;
        ks = ks < 0 ? 0 : (ks > NWL - 1 ? NWL - 1 : ks);
        int bv = mv[(b * NL + st) * NWL + ks];
        out[b] = (float)st;
        out[NB + b] = (float)en;
        out[2 * NB + b] = best;
        out[3 * NB + b] = (float)bv;
    }
}

extern "C" void kernel_launch(void* const* d_in, const int* in_sizes, int n_in,
                              void* d_out, int out_size, void* d_ws, size_t ws_size,
                              hipStream_t stream) {
    const float* word = (const float*)d_in[0];   // (B,L,D) f32
    const float* unit = (const float*)d_in[1];   // (U,D) f32
    const int* seg = (const int*)d_in[2];        // (V,MAXWL) i32
    const int* vlen = (const int*)d_in[3];       // (V,) i32
    float* out = (float*)d_out;                  // [start|end|score|vocab|dense]
    char* ws = (char*)d_ws;
    float* sim = (float*)ws;                     // B*L*U f32 = 2,048,000 B
    int* mv = (int*)(ws + 2048000);              // B*L*NWL i32 = 28,672 B
    float* dense = out + 4 * NB;

    k_sim<<<NB * 4 * 16, 256, 0, stream>>>(word, unit, sim);
    k_extract<<<NB * NL, NT, 0, stream>>>(sim, seg, vlen, dense, mv);
    k_final<<<NB, 256, 0, stream>>>(dense, mv, out);
}